// Round 14
// baseline (79.119 us; speedup 1.0000x reference)
//
#include <hip/hip_runtime.h>

typedef int   int4v  __attribute__((ext_vector_type(4)));
typedef char  char8v __attribute__((ext_vector_type(8)));

#define NROWS 8192
#define DIM 512
#define ROWB 512           // DIM * 1 byte (i8)

#define AS1(p) ((const __attribute__((address_space(1))) void*)(p))
#define AS3(p) ((__attribute__((address_space(3))) void*)(p))

#if __has_builtin(__builtin_amdgcn_exp2f)
#define EXP2(x) __builtin_amdgcn_exp2f(x)
#else
#define EXP2(x) exp2f(x)
#endif

// ---------------------------------------------------------------------------
// Kernel 1: wave-per-row normalize + i8 quantize + diag + rowsum zero.
// (identical to R7/R13 — proven)
// ---------------------------------------------------------------------------
__global__ __launch_bounds__(256) void prep_kernel(
    const float* __restrict__ v, const float* __restrict__ u,
    char* __restrict__ vq, char* __restrict__ uq,
    float* __restrict__ sa, float* __restrict__ sb,
    float* __restrict__ diag, float* __restrict__ rowsum)
{
    const int row  = blockIdx.x * 4 + (threadIdx.x >> 6);
    const int lane = threadIdx.x & 63;
    const float4* vr = reinterpret_cast<const float4*>(v + (size_t)row * DIM);
    const float4* ur = reinterpret_cast<const float4*>(u + (size_t)row * DIM);
    const float4 a0 = vr[lane * 2], a1 = vr[lane * 2 + 1];
    const float4 b0 = ur[lane * 2], b1 = ur[lane * 2 + 1];
    float av[8] = {a0.x, a0.y, a0.z, a0.w, a1.x, a1.y, a1.z, a1.w};
    float bv[8] = {b0.x, b0.y, b0.z, b0.w, b1.x, b1.y, b1.z, b1.w};
    float sv = 0.f, su = 0.f, sd = 0.f, mv = 0.f, mu = 0.f;
#pragma unroll
    for (int i = 0; i < 8; ++i) {
        sv += av[i] * av[i];
        su += bv[i] * bv[i];
        sd += av[i] * bv[i];
        mv = fmaxf(mv, fabsf(av[i]));
        mu = fmaxf(mu, fabsf(bv[i]));
    }
#pragma unroll
    for (int m = 32; m; m >>= 1) {
        sv += __shfl_xor(sv, m);
        su += __shfl_xor(su, m);
        sd += __shfl_xor(sd, m);
        mv = fmaxf(mv, __shfl_xor(mv, m));
        mu = fmaxf(mu, __shfl_xor(mu, m));
    }
    const float rv = 1.0f / fmaxf(sqrtf(sv), 1e-8f);
    const float ru = 1.0f / fmaxf(sqrtf(su), 1e-8f);
    const float qv = 127.0f / fmaxf(mv, 1e-20f);
    const float qu = 127.0f / fmaxf(mu, 1e-20f);
    char8v cv, cu;
#pragma unroll
    for (int i = 0; i < 8; ++i) {
        cv[i] = (char)__float2int_rn(av[i] * qv);
        cu[i] = (char)__float2int_rn(bv[i] * qu);
    }
    reinterpret_cast<char8v*>(vq + (size_t)row * DIM)[lane] = cv;
    reinterpret_cast<char8v*>(uq + (size_t)row * DIM)[lane] = cu;
    if (lane == 0) {
        sa[row] = mv * rv / 127.0f;
        sb[row] = mu * ru / 127.0f;
        diag[row] = sd * rv * ru;
        rowsum[row] = 0.0f;
    }
}

// ---------------------------------------------------------------------------
// Kernel 2: 64-rows-per-wave A-STATIONARY i8 GEMM (R14).
// R13 diagnosis: at 32 rows/wave the LDS invariant is 1 GB (~19us of the
// 41.6us kernel); halving it requires 64 rows/wave, which only fits with A
// stationary: A 128 VGPR + acc 64 + transients ~= 240 < 256 cap at
// __launch_bounds__(256,2) (the config proven spill-free in R7/R9).
// Per step the wave issues 8 ds_read : 32 MFMA — MFMA-dominant mix.
// Stage granularity = full col-tile (64 cols x K=512 = 32 KB), double-
// buffered (64 KB LDS), stage issued BEFORE compute so __syncthreads'
// vmcnt(0) drain is covered by ~128 MFMAs (catalog "minimum 2-phase").
// Only 8 barriers total. XOR swizzle both-sides (G21): LDS[c][klds] holds
// global k = klds ^ ((c&7)<<4); read klds = k ^ ((c&7)<<4) -> <=2-way.
// Block = 4 waves x 64 rows = 256 rows; sweeps 8 col-tiles of 64.
// Grid 32 x 16 = 512 blocks (2/CU).
// ---------------------------------------------------------------------------
__global__ __launch_bounds__(256, 2) void simsum_kernel(
    const char* __restrict__ A, const char* __restrict__ Bq,
    const float* __restrict__ sa, const float* __restrict__ sb,
    float* __restrict__ rowsum)
{
    __shared__ __align__(16) char ldsB[2][32768];  // [buf][64 cols x 512 B]
    const int tid  = threadIdx.x;
    const int wave = tid >> 6;
    const int lane = tid & 63;
    const int ln15 = lane & 15;
    const int lhi  = lane >> 4;

    const int rb = blockIdx.x;                 // 0..31 -> 256 rows each
    const int cg = blockIdx.y;                 // 0..15 -> 8 col-tiles of 64
    const int grow  = rb * 256 + wave * 64;    // this wave's 64 rows
    const int gcol0 = cg * 512;                // this block's 512 cols

    // ---- A stationary: 64 rows x K=512 -> Areg[t][kk][m] = 32 int4v = 128 VGPR
    int4v Areg[4][2][4];
#pragma unroll
    for (int t = 0; t < 4; ++t)
#pragma unroll
        for (int kk = 0; kk < 2; ++kk)
#pragma unroll
            for (int m = 0; m < 4; ++m) {
                const int r = grow + m * 16 + ln15;
                Areg[t][kk][m] = *reinterpret_cast<const int4v*>(
                    A + (size_t)r * ROWB + t * 128 + kk * 64 + lhi * 16);
            }

    // per-row dequant scale (x 2*log2e) for this thread's 16 rows
    const float C2 = 2.885390081777927f;   // 2 * log2(e)
    float ga[4][4];
#pragma unroll
    for (int m = 0; m < 4; ++m)
#pragma unroll
        for (int rr = 0; rr < 4; ++rr)
            ga[m][rr] = sa[grow + m * 16 + lhi * 4 + rr] * C2;

    // ---- staging: 8 gloads/thread cover one 32 KB col-tile (all K).
    // LDS linear slot (i*4096 + tid*16) = col c = i*8 + (tid>>5),
    // klds = (tid&31)*16; source global k = klds ^ ((c&7)<<4)  (G21 pair).
    auto stageB = [&](int buf, int ct) {
#pragma unroll
        for (int i = 0; i < 8; ++i) {
            const int c    = i * 8 + (tid >> 5);
            const int koff = ((tid & 31) * 16) ^ ((c & 7) << 4);
            const int col  = gcol0 + ct * 64 + c;
            __builtin_amdgcn_global_load_lds(
                AS1(Bq + (size_t)col * ROWB + koff),
                AS3(&ldsB[buf][i * 4096 + tid * 16]), 16, 0, 0);
        }
    };

    stageB(0, 0);
    __syncthreads();

    int buf = 0;
    for (int ct = 0; ct < 8; ++ct) {
        if (ct + 1 < 8) stageB(buf ^ 1, ct + 1);   // issue BEFORE compute

        int4v acc[4][4];
#pragma unroll
        for (int m = 0; m < 4; ++m)
#pragma unroll
            for (int n = 0; n < 4; ++n)
                acc[m][n] = (int4v){0, 0, 0, 0};

#pragma unroll
        for (int t = 0; t < 4; ++t)
#pragma unroll
            for (int kk = 0; kk < 2; ++kk) {
                int4v Bf[4];
#pragma unroll
                for (int n = 0; n < 4; ++n) {
                    const int c = n * 16 + ln15;
                    const int klds = (t * 128 + kk * 64 + lhi * 16) ^
                                     ((c & 7) << 4);
                    Bf[n] = *reinterpret_cast<const int4v*>(
                        &ldsB[buf][c * 512 + klds]);
                }
#pragma unroll
                for (int m = 0; m < 4; ++m)
#pragma unroll
                    for (int n = 0; n < 4; ++n)
                        acc[m][n] = __builtin_amdgcn_mfma_i32_16x16x64_i8(
                            Areg[t][kk][m], Bf[n], acc[m][n], 0, 0, 0);
            }

        // epilogue for this 64-col tile (registers only, no LDS)
        float sbv[4];
#pragma unroll
        for (int n = 0; n < 4; ++n)
            sbv[n] = sb[gcol0 + ct * 64 + n * 16 + ln15];
#pragma unroll
        for (int m = 0; m < 4; ++m)
#pragma unroll
            for (int rr = 0; rr < 4; ++rr) {
                const float g = ga[m][rr];
                float s = 0.f;
#pragma unroll
                for (int n = 0; n < 4; ++n)
                    s += EXP2((float)acc[m][n][rr] * g * sbv[n]);
                s += __shfl_xor(s, 1);
                s += __shfl_xor(s, 2);
                s += __shfl_xor(s, 4);
                s += __shfl_xor(s, 8);
                if (ln15 == 0)
                    atomicAdd(&rowsum[grow + m * 16 + lhi * 4 + rr], s);
            }

        __syncthreads();   // drains vmcnt: next tile (issued pre-compute) landed
        buf ^= 1;
    }
}

// ---------------------------------------------------------------------------
// Kernel 3: loss_i = log(exp(2*diag_i) + rowsum_i) - 2*diag_i
// ---------------------------------------------------------------------------
__global__ __launch_bounds__(256) void loss_kernel(
    const float* __restrict__ diag, const float* __restrict__ rowsum,
    float* __restrict__ out)
{
    const int i = blockIdx.x * 256 + threadIdx.x;
    const float d2 = diag[i] * 2.0f;
    out[i] = logf(expf(d2) + rowsum[i]) - d2;
}

extern "C" void kernel_launch(void* const* d_in, const int* in_sizes, int n_in,
                              void* d_out, int out_size, void* d_ws, size_t ws_size,
                              hipStream_t stream) {
    const float* v = (const float*)d_in[0];
    const float* u = (const float*)d_in[1];
    float* out = (float*)d_out;
    char* ws = (char*)d_ws;
    char*  vq     = ws;                                   // 4 MiB
    char*  uq     = ws + (size_t)4194304;                 // 4 MiB
    float* sa     = (float*)(ws + (size_t)8388608);       // 32 KiB
    float* sb     = (float*)(ws + (size_t)8388608 + 32768);
    float* diag   = (float*)(ws + (size_t)8388608 + 65536);
    float* rowsum = (float*)(ws + (size_t)8388608 + 98304);

    prep_kernel<<<NROWS / 4, 256, 0, stream>>>(v, u, vq, uq, sa, sb, diag, rowsum);
    dim3 grid(32, 16);
    simsum_kernel<<<grid, 256, 0, stream>>>(vq, uq, sa, sb, rowsum);
    loss_kernel<<<NROWS / 256, 256, 0, stream>>>(diag, rowsum, out);
}

// Round 15
// 67.961 us; speedup vs baseline: 1.1642x; 1.1642x over previous
//
#include <hip/hip_runtime.h>

typedef int   int4v  __attribute__((ext_vector_type(4)));
typedef char  char8v __attribute__((ext_vector_type(8)));

#define NROWS 8192
#define DIM 512
#define ROWB 512           // DIM * 1 byte (i8)
#define NT 4               // K-steps of BK=128 per col-tile
#define SWEEP 8            // col-tiles of 64 per block

#define AS1(p) ((const __attribute__((address_space(1))) void*)(p))
#define AS3(p) ((__attribute__((address_space(3))) void*)(p))

#if __has_builtin(__builtin_amdgcn_exp2f)
#define EXP2(x) __builtin_amdgcn_exp2f(x)
#else
#define EXP2(x) exp2f(x)
#endif

// ---------------------------------------------------------------------------
// Kernel 1: wave-per-row normalize + i8 quantize + diag + rowsum zero.
// (identical to R7/R13 — proven)
// ---------------------------------------------------------------------------
__global__ __launch_bounds__(256) void prep_kernel(
    const float* __restrict__ v, const float* __restrict__ u,
    char* __restrict__ vq, char* __restrict__ uq,
    float* __restrict__ sa, float* __restrict__ sb,
    float* __restrict__ diag, float* __restrict__ rowsum)
{
    const int row  = blockIdx.x * 4 + (threadIdx.x >> 6);
    const int lane = threadIdx.x & 63;
    const float4* vr = reinterpret_cast<const float4*>(v + (size_t)row * DIM);
    const float4* ur = reinterpret_cast<const float4*>(u + (size_t)row * DIM);
    const float4 a0 = vr[lane * 2], a1 = vr[lane * 2 + 1];
    const float4 b0 = ur[lane * 2], b1 = ur[lane * 2 + 1];
    float av[8] = {a0.x, a0.y, a0.z, a0.w, a1.x, a1.y, a1.z, a1.w};
    float bv[8] = {b0.x, b0.y, b0.z, b0.w, b1.x, b1.y, b1.z, b1.w};
    float sv = 0.f, su = 0.f, sd = 0.f, mv = 0.f, mu = 0.f;
#pragma unroll
    for (int i = 0; i < 8; ++i) {
        sv += av[i] * av[i];
        su += bv[i] * bv[i];
        sd += av[i] * bv[i];
        mv = fmaxf(mv, fabsf(av[i]));
        mu = fmaxf(mu, fabsf(bv[i]));
    }
#pragma unroll
    for (int m = 32; m; m >>= 1) {
        sv += __shfl_xor(sv, m);
        su += __shfl_xor(su, m);
        sd += __shfl_xor(sd, m);
        mv = fmaxf(mv, __shfl_xor(mv, m));
        mu = fmaxf(mu, __shfl_xor(mu, m));
    }
    const float rv = 1.0f / fmaxf(sqrtf(sv), 1e-8f);
    const float ru = 1.0f / fmaxf(sqrtf(su), 1e-8f);
    const float qv = 127.0f / fmaxf(mv, 1e-20f);
    const float qu = 127.0f / fmaxf(mu, 1e-20f);
    char8v cv, cu;
#pragma unroll
    for (int i = 0; i < 8; ++i) {
        cv[i] = (char)__float2int_rn(av[i] * qv);
        cu[i] = (char)__float2int_rn(bv[i] * qu);
    }
    reinterpret_cast<char8v*>(vq + (size_t)row * DIM)[lane] = cv;
    reinterpret_cast<char8v*>(uq + (size_t)row * DIM)[lane] = cu;
    if (lane == 0) {
        sa[row] = mv * rv / 127.0f;
        sb[row] = mu * ru / 127.0f;
        diag[row] = sd * rv * ru;
        rowsum[row] = 0.0f;
    }
}

// ---------------------------------------------------------------------------
// Kernel 2: R13's ring/counted-vmcnt structure with acc HALVED to fit the
// 128-combined-register HW quantum (occupancy model fitting R5-R13: combined
// VGPR+AGPR rounds up to {64,128,256}; waves/SIMD = 512/quantum. R13's 180
// -> 256 -> 2 waves/SIMD was the overlap wall).
// Wave = 32 rows x 64 cols/step: Areg 64 + acc 32 + Bf 8 + misc ~20 ~= 125.
// __launch_bounds__(256,4) pins cap at 128 combined (need ~125; R8's
// failure was need 190 at cap 128 — here the gap is ~0).
// Ring 4 x 8 KB LDS (32 KB/block), stage step g+2 at step g (2 gloads),
// counted vmcnt(2) per step (never 0 until tail), raw s_barrier, proven
// R5/R7/R13 XOR swizzle byte-for-byte. 32 steps/block.
// Block = 4 waves x 32 rows = 128 rows, sweeps 8 col-tiles of 64 (512 cols).
// Grid 64 x 16 = 1024 blocks -> 4 blocks/CU at the 128 quantum.
// ---------------------------------------------------------------------------
__global__ __launch_bounds__(256, 4) void simsum_kernel(
    const char* __restrict__ A, const char* __restrict__ Bq,
    const float* __restrict__ sa, const float* __restrict__ sb,
    float* __restrict__ rowsum)
{
    __shared__ __align__(16) char ldsB[4][8192];   // ring: 4 x (64 cols x 128 B)
    const int tid  = threadIdx.x;
    const int wave = tid >> 6;
    const int lane = tid & 63;
    const int ln15 = lane & 15;
    const int lhi  = lane >> 4;
    const int swz  = (ln15 & 7) << 4;          // read-side XOR (= col&7 <<4)

    const int brow = blockIdx.x;               // 0..63 -> 128 rows each
    const int bgrp = blockIdx.y;               // 0..15 -> 8 col-tiles of 64
    const int growA = brow * 128 + wave * 32;  // this wave's 32 rows
    const int gcol0 = bgrp * (SWEEP * 64);     // this block's 512 cols

    // ---- A into registers: [t][kk][m], 16 x int4v = 64 VGPR (R7 proven) ----
    int4v Areg[NT][2][2];
#pragma unroll
    for (int t = 0; t < NT; ++t)
#pragma unroll
        for (int kk = 0; kk < 2; ++kk)
#pragma unroll
            for (int m = 0; m < 2; ++m) {
                const int r = growA + m * 16 + ln15;
                Areg[t][kk][m] = *reinterpret_cast<const int4v*>(
                    A + (size_t)r * ROWB + t * 128 + kk * 64 + lhi * 16);
            }

    // per-row dequant scale (x 2*log2e) for this thread's 8 rows
    const float C2 = 2.885390081777927f;   // 2 * log2(e)
    float ga[2][4];
#pragma unroll
    for (int m = 0; m < 2; ++m)
#pragma unroll
        for (int rr = 0; rr < 4; ++rr)
            ga[m][rr] = sa[growA + m * 16 + lhi * 4 + rr] * C2;

    // staging: 2 gloads/thread cover one 8 KB col-tile-K-step; linear LDS
    // dest, source k-chunk pre-swizzled (G21 pairing, 0-conflict R5/R7/R13).
    const int r0   = tid >> 3;
    const int sl16 = (((tid & 7) ^ ((tid >> 3) & 7)) << 4);

    auto stageB = [&](int bi, int gs) {       // gs = global step 0..31
        const int ct = gs >> 2;               // col-tile 0..7
        const int kt = gs & 3;                // K-step 0..3
#pragma unroll
        for (int q = 0; q < 2; ++q) {
            const int col = gcol0 + ct * 64 + q * 32 + r0;
            __builtin_amdgcn_global_load_lds(
                AS1(Bq + (size_t)col * ROWB + kt * 128 + sl16),
                AS3(&ldsB[bi][q * 4096 + tid * 16]), 16, 0, 0);
        }
    };

    // ---- prologue: depth-2 ----
    stageB(0, 0);
    stageB(1, 1);
    asm volatile("s_waitcnt vmcnt(2)" ::: "memory");   // step 0 landed
    asm volatile("s_barrier" ::: "memory");

    for (int s = 0; s < SWEEP; ++s) {
        int4v acc[2][4];
#pragma unroll
        for (int m = 0; m < 2; ++m)
#pragma unroll
            for (int n = 0; n < 4; ++n)
                acc[m][n] = (int4v){0, 0, 0, 0};

#pragma unroll
        for (int tt = 0; tt < NT; ++tt) {
            const int g = s * 4 + tt;
            if (g + 2 < 32) stageB((tt + 2) & 3, g + 2);
#pragma unroll
            for (int kk = 0; kk < 2; ++kk) {
                int4v Bf[4];
#pragma unroll
                for (int n = 0; n < 4; ++n) {
                    const int c = n * 16 + ln15;
                    Bf[n] = *reinterpret_cast<const int4v*>(
                        &ldsB[tt & 3][c * 128 + ((kk * 64 + lhi * 16) ^ swz)]);
                }
#pragma unroll
                for (int m = 0; m < 2; ++m)
#pragma unroll
                    for (int n = 0; n < 4; ++n)
                        acc[m][n] = __builtin_amdgcn_mfma_i32_16x16x64_i8(
                            Areg[tt][kk][m], Bf[n], acc[m][n], 0, 0, 0);
            }
            // counted wait: g+1's 2 loads drained, g+2's stay in flight
            if (g < 30)       asm volatile("s_waitcnt vmcnt(2)" ::: "memory");
            else if (g == 30) asm volatile("s_waitcnt vmcnt(0)" ::: "memory");
            if (g < 31)       asm volatile("s_barrier" ::: "memory");
        }

        // epilogue for this 64-col tile: exp2 + shfl reduce + 1 atomic/row
        float sbv[4];
#pragma unroll
        for (int n = 0; n < 4; ++n)
            sbv[n] = sb[gcol0 + s * 64 + n * 16 + ln15];
#pragma unroll
        for (int m = 0; m < 2; ++m)
#pragma unroll
            for (int rr = 0; rr < 4; ++rr) {
                const float g2 = ga[m][rr];
                float sum = 0.f;
#pragma unroll
                for (int n = 0; n < 4; ++n)
                    sum += EXP2((float)acc[m][n][rr] * g2 * sbv[n]);
                sum += __shfl_xor(sum, 1);
                sum += __shfl_xor(sum, 2);
                sum += __shfl_xor(sum, 4);
                sum += __shfl_xor(sum, 8);
                if (ln15 == 0)
                    atomicAdd(&rowsum[growA + m * 16 + lhi * 4 + rr], sum);
            }
    }
}

// ---------------------------------------------------------------------------
// Kernel 3: loss_i = log(exp(2*diag_i) + rowsum_i) - 2*diag_i
// ---------------------------------------------------------------------------
__global__ __launch_bounds__(256) void loss_kernel(
    const float* __restrict__ diag, const float* __restrict__ rowsum,
    float* __restrict__ out)
{
    const int i = blockIdx.x * 256 + threadIdx.x;
    const float d2 = diag[i] * 2.0f;
    out[i] = logf(expf(d2) + rowsum[i]) - d2;
}

extern "C" void kernel_launch(void* const* d_in, const int* in_sizes, int n_in,
                              void* d_out, int out_size, void* d_ws, size_t ws_size,
                              hipStream_t stream) {
    const float* v = (const float*)d_in[0];
    const float* u = (const float*)d_in[1];
    float* out = (float*)d_out;
    char* ws = (char*)d_ws;
    char*  vq     = ws;                                   // 4 MiB
    char*  uq     = ws + (size_t)4194304;                 // 4 MiB
    float* sa     = (float*)(ws + (size_t)8388608);       // 32 KiB
    float* sb     = (float*)(ws + (size_t)8388608 + 32768);
    float* diag   = (float*)(ws + (size_t)8388608 + 65536);
    float* rowsum = (float*)(ws + (size_t)8388608 + 98304);

    prep_kernel<<<NROWS / 4, 256, 0, stream>>>(v, u, vq, uq, sa, sb, diag, rowsum);
    dim3 grid(64, 16);
    simsum_kernel<<<grid, 256, 0, stream>>>(vq, uq, sa, sb, rowsum);
    loss_kernel<<<NROWS / 256, 256, 0, stream>>>(diag, rowsum, out);
}

// Round 16
// 65.897 us; speedup vs baseline: 1.2006x; 1.0313x over previous
//
#include <hip/hip_runtime.h>

typedef int   int4v  __attribute__((ext_vector_type(4)));
typedef char  char8v __attribute__((ext_vector_type(8)));

#define NROWS 8192
#define DIM 512
#define ROWB 512           // DIM * 1 byte (i8)
#define NT 4               // K-steps of BK=128 per col-tile
#define SWEEP 8            // col-tiles of 64 per block

#define AS1(p) ((const __attribute__((address_space(1))) void*)(p))
#define AS3(p) ((__attribute__((address_space(3))) void*)(p))

#if __has_builtin(__builtin_amdgcn_exp2f)
#define EXP2(x) __builtin_amdgcn_exp2f(x)
#else
#define EXP2(x) exp2f(x)
#endif

// ---------------------------------------------------------------------------
// Kernel 1: wave-per-row normalize + i8 quantize + diag + rowsum zero.
// (identical to R7/R13 — proven)
// ---------------------------------------------------------------------------
__global__ __launch_bounds__(256) void prep_kernel(
    const float* __restrict__ v, const float* __restrict__ u,
    char* __restrict__ vq, char* __restrict__ uq,
    float* __restrict__ sa, float* __restrict__ sb,
    float* __restrict__ diag, float* __restrict__ rowsum)
{
    const int row  = blockIdx.x * 4 + (threadIdx.x >> 6);
    const int lane = threadIdx.x & 63;
    const float4* vr = reinterpret_cast<const float4*>(v + (size_t)row * DIM);
    const float4* ur = reinterpret_cast<const float4*>(u + (size_t)row * DIM);
    const float4 a0 = vr[lane * 2], a1 = vr[lane * 2 + 1];
    const float4 b0 = ur[lane * 2], b1 = ur[lane * 2 + 1];
    float av[8] = {a0.x, a0.y, a0.z, a0.w, a1.x, a1.y, a1.z, a1.w};
    float bv[8] = {b0.x, b0.y, b0.z, b0.w, b1.x, b1.y, b1.z, b1.w};
    float sv = 0.f, su = 0.f, sd = 0.f, mv = 0.f, mu = 0.f;
#pragma unroll
    for (int i = 0; i < 8; ++i) {
        sv += av[i] * av[i];
        su += bv[i] * bv[i];
        sd += av[i] * bv[i];
        mv = fmaxf(mv, fabsf(av[i]));
        mu = fmaxf(mu, fabsf(bv[i]));
    }
#pragma unroll
    for (int m = 32; m; m >>= 1) {
        sv += __shfl_xor(sv, m);
        su += __shfl_xor(su, m);
        sd += __shfl_xor(sd, m);
        mv = fmaxf(mv, __shfl_xor(mv, m));
        mu = fmaxf(mu, __shfl_xor(mu, m));
    }
    const float rv = 1.0f / fmaxf(sqrtf(sv), 1e-8f);
    const float ru = 1.0f / fmaxf(sqrtf(su), 1e-8f);
    const float qv = 127.0f / fmaxf(mv, 1e-20f);
    const float qu = 127.0f / fmaxf(mu, 1e-20f);
    char8v cv, cu;
#pragma unroll
    for (int i = 0; i < 8; ++i) {
        cv[i] = (char)__float2int_rn(av[i] * qv);
        cu[i] = (char)__float2int_rn(bv[i] * qu);
    }
    reinterpret_cast<char8v*>(vq + (size_t)row * DIM)[lane] = cv;
    reinterpret_cast<char8v*>(uq + (size_t)row * DIM)[lane] = cu;
    if (lane == 0) {
        sa[row] = mv * rv / 127.0f;
        sb[row] = mu * ru / 127.0f;
        diag[row] = sd * rv * ru;
        rowsum[row] = 0.0f;
    }
}

// ---------------------------------------------------------------------------
// Kernel 2: WAVE-PRIVATE, ZERO-BARRIER self-paced i8 GEMM (R16).
// R13's residual stall is the 32x workgroup barrier convoying 4 waves (the
// slowest wave's L2 latency gates all). The barrier exists only because B
// staging is shared. Here each wave owns a private 2x8KB LDS ring, issues
// its OWN 8 global_load_lds for step g+1, waits a counted vmcnt(8) (its own
// step-g loads only), computes, flips. NO barriers anywhere — waves drift
// freely; the 2 waves/SIMD hide each other's latency (m114).
// Cost: B staged per-wave (L2 reads 0.27->1 GB, LDS 2 GB total) — both
// pipes land ~29us aggregate, parallel to the 17.4us MFMA floor.
// Proven pieces unchanged: A-stationary 64 VGPR, acc 32, G21 swizzle pair,
// rs-accumulated epilogue, __launch_bounds__(256,2) (only spill-free cfg).
// Block = 4 independent waves x 32 rows; sweeps 8 col-tiles of 64 (512 cols).
// Grid 64 x 16 = 1024 blocks, LDS 64 KB/block -> 2 blocks/CU.
// ---------------------------------------------------------------------------
__global__ __launch_bounds__(256, 2) void simsum_kernel(
    const char* __restrict__ A, const char* __restrict__ Bq,
    const float* __restrict__ sa, const float* __restrict__ sb,
    float* __restrict__ rowsum)
{
    __shared__ __align__(16) char lds[4][2][8192];  // [wave][buf][64c x 128B]
    const int tid  = threadIdx.x;
    const int wave = tid >> 6;
    const int lane = tid & 63;
    const int ln15 = lane & 15;
    const int lhi  = lane >> 4;
    const int swz  = (ln15 & 7) << 4;          // read-side XOR (= col&7 <<4)

    const int brow = blockIdx.x;               // 0..63 -> 128 rows each
    const int bgrp = blockIdx.y;               // 0..15 -> 8 col-tiles of 64
    const int growA = brow * 128 + wave * 32;  // this wave's 32 rows
    const int gcol0 = bgrp * (SWEEP * 64);     // this block's 512 cols

    // ---- A into registers: [t][kk][m], 16 x int4v = 64 VGPR (proven) ----
    int4v Areg[NT][2][2];
#pragma unroll
    for (int t = 0; t < NT; ++t)
#pragma unroll
        for (int kk = 0; kk < 2; ++kk)
#pragma unroll
            for (int m = 0; m < 2; ++m) {
                const int r = growA + m * 16 + ln15;
                Areg[t][kk][m] = *reinterpret_cast<const int4v*>(
                    A + (size_t)r * ROWB + t * 128 + kk * 64 + lhi * 16);
            }

    // per-row dequant scale (x 2*log2e) for this thread's 8 rows
    const float C2 = 2.885390081777927f;   // 2 * log2(e)
    float ga[2][4];
#pragma unroll
    for (int m = 0; m < 2; ++m)
#pragma unroll
        for (int rr = 0; rr < 4; ++rr)
            ga[m][rr] = sa[growA + m * 16 + lhi * 4 + rr] * C2;

    float rs[2][4];
#pragma unroll
    for (int m = 0; m < 2; ++m)
#pragma unroll
        for (int rr = 0; rr < 4; ++rr)
            rs[m][rr] = 0.f;

    // wave-private staging: 8 gloads/lane-instr cover one 8 KB col-tile-
    // K-step. LDS linear slot (q*1024 + lane*16): col c = q*8 + (lane>>3),
    // k-chunk (lane&7)*16; global source k pre-swizzled by (c&7)<<4 (G21).
    const int l0   = lane >> 3;
    const int sl16 = (((lane & 7) ^ ((lane >> 3) & 7)) << 4);
    char* myl = &lds[wave][0][0];

    auto stageW = [&](int bi, int gs) {        // gs = global step 0..31
        const int ct = gs >> 2;                // col-tile 0..7
        const int kt = gs & 3;                 // K-step 0..3
#pragma unroll
        for (int q = 0; q < 8; ++q) {
            const int col = gcol0 + ct * 64 + q * 8 + l0;
            __builtin_amdgcn_global_load_lds(
                AS1(Bq + (size_t)col * ROWB + kt * 128 + sl16),
                AS3(myl + bi * 8192 + q * 1024 + lane * 16), 16, 0, 0);
        }
    };

    // ---- prologue: stage step 0 into buf 0 ----
    stageW(0, 0);

    int buf = 0;
    for (int s = 0; s < SWEEP; ++s) {
        int4v acc[2][4];
#pragma unroll
        for (int m = 0; m < 2; ++m)
#pragma unroll
            for (int n = 0; n < 4; ++n)
                acc[m][n] = (int4v){0, 0, 0, 0};

#pragma unroll
        for (int tt = 0; tt < NT; ++tt) {
            const int g = s * 4 + tt;
            if (g + 1 < 32) stageW(buf ^ 1, g + 1);    // issue next first
            // wait own step-g loads: outstanding = g's 8 (old) + g+1's 8
            if (g < 31) asm volatile("s_waitcnt vmcnt(8)" ::: "memory");
            else        asm volatile("s_waitcnt vmcnt(0)" ::: "memory");
#pragma unroll
            for (int kk = 0; kk < 2; ++kk) {
                int4v Bf[4];
#pragma unroll
                for (int n = 0; n < 4; ++n) {
                    const int c = n * 16 + ln15;
                    Bf[n] = *reinterpret_cast<const int4v*>(
                        myl + buf * 8192 + c * 128 +
                        ((kk * 64 + lhi * 16) ^ swz));
                }
#pragma unroll
                for (int m = 0; m < 2; ++m)
#pragma unroll
                    for (int n = 0; n < 4; ++n)
                        acc[m][n] = __builtin_amdgcn_mfma_i32_16x16x64_i8(
                            Areg[tt][kk][m], Bf[n], acc[m][n], 0, 0, 0);
            }
            buf ^= 1;
        }

        // epilogue for this 64-col tile: accumulate lane-local partials
        float sbv[4];
#pragma unroll
        for (int n = 0; n < 4; ++n)
            sbv[n] = sb[gcol0 + s * 64 + n * 16 + ln15];
#pragma unroll
        for (int m = 0; m < 2; ++m)
#pragma unroll
            for (int rr = 0; rr < 4; ++rr) {
                const float g2 = ga[m][rr];
#pragma unroll
                for (int n = 0; n < 4; ++n)
                    rs[m][rr] += EXP2((float)acc[m][n][rr] * g2 * sbv[n]);
            }
    }

    // final cross-lane reduce (cols live across ln15) + one atomic per row
#pragma unroll
    for (int m = 0; m < 2; ++m)
#pragma unroll
        for (int rr = 0; rr < 4; ++rr) {
            float s = rs[m][rr];
            s += __shfl_xor(s, 1);
            s += __shfl_xor(s, 2);
            s += __shfl_xor(s, 4);
            s += __shfl_xor(s, 8);
            if (ln15 == 0)
                atomicAdd(&rowsum[growA + m * 16 + lhi * 4 + rr], s);
        }
}

// ---------------------------------------------------------------------------
// Kernel 3: loss_i = log(exp(2*diag_i) + rowsum_i) - 2*diag_i
// ---------------------------------------------------------------------------
__global__ __launch_bounds__(256) void loss_kernel(
    const float* __restrict__ diag, const float* __restrict__ rowsum,
    float* __restrict__ out)
{
    const int i = blockIdx.x * 256 + threadIdx.x;
    const float d2 = diag[i] * 2.0f;
    out[i] = logf(expf(d2) + rowsum[i]) - d2;
}

extern "C" void kernel_launch(void* const* d_in, const int* in_sizes, int n_in,
                              void* d_out, int out_size, void* d_ws, size_t ws_size,
                              hipStream_t stream) {
    const float* v = (const float*)d_in[0];
    const float* u = (const float*)d_in[1];
    float* out = (float*)d_out;
    char* ws = (char*)d_ws;
    char*  vq     = ws;                                   // 4 MiB
    char*  uq     = ws + (size_t)4194304;                 // 4 MiB
    float* sa     = (float*)(ws + (size_t)8388608);       // 32 KiB
    float* sb     = (float*)(ws + (size_t)8388608 + 32768);
    float* diag   = (float*)(ws + (size_t)8388608 + 65536);
    float* rowsum = (float*)(ws + (size_t)8388608 + 98304);

    prep_kernel<<<NROWS / 4, 256, 0, stream>>>(v, u, vq, uq, sa, sb, diag, rowsum);
    dim3 grid(64, 16);
    simsum_kernel<<<grid, 256, 0, stream>>>(vq, uq, sa, sb, rowsum);
    loss_kernel<<<NROWS / 256, 256, 0, stream>>>(diag, rowsum, out);
}